// Round 11
// baseline (186.475 us; speedup 1.0000x reference)
//
#include <hip/hip_runtime.h>

// Problem constants (fixed by the reference).
constexpr int IN_CH = 4;
constexpr int KS    = 40;
constexpr int L_IN  = 8192;
constexpr int L_OUT = L_IN - KS + 1;   // 8153
constexpr int NF    = 600;
constexpr int BATCH = 32;
constexpr int PADL  = 8200;            // padded floats per xp row (mult of 4, zero-tail)
constexpr int PADL4 = PADL / 4;        // 2050 float4s per row
constexpr int NPH   = 4;               // phase-shifted copies
constexpr int TAPF  = 4800;            // tap table floats (600*8); xp starts here (16B-aligned)
constexpr int RPB   = 8;               // consecutive rows per block
constexpr int NROW  = NF * BATCH;      // 19200
constexpr int NBLK  = NROW / RPB;      // 2400 blocks
constexpr int RPX   = NROW / 8;        // 2400 rows per XCD slice

typedef float floatx4 __attribute__((ext_vector_type(4)));

// ---- Kernel 1: taps. rec[k] = {c0,p0,c1,p1,w0,w1,0,0} (ints bitcast) ----
__global__ void tap_kernel(const float* __restrict__ w, float* __restrict__ ws) {
    const int k = blockIdx.x * 256 + threadIdx.x;
    if (k >= NF) return;
    const float* wk = w + (size_t)k * IN_CH * KS;
    int n = 0; int cc[2] = {0, 0}, pp[2] = {0, 0}; float val[2] = {0.f, 0.f};
    for (int i = 0; i < IN_CH * KS; ++i) {
        const float v = wk[i];
        if (v != 0.0f && n < 2) { cc[n] = i / KS; pp[n] = i % KS; val[n] = v; ++n; }
    }
    if (n == 1) { cc[1] = cc[0]; pp[1] = pp[0]; val[1] = 0.0f; }   // defensive
    float* r = ws + (size_t)k * 8;
    r[0] = __int_as_float(cc[0]); r[1] = __int_as_float(pp[0]);
    r[2] = __int_as_float(cc[1]); r[3] = __int_as_float(pp[1]);
    r[4] = val[0];                r[5] = val[1];
    r[6] = 0.f;                   r[7] = 0.f;
}

// ---- Kernel 2: build 4 phase-shifted copies of x in ws ----
// xp[ph][b][c][m] = x[b][c][m+ph] (0 past the end). 16.8 MB; makes every
// main-kernel read an ALIGNED lane-contiguous dwordx4 (full cache-line use).
__global__ __launch_bounds__(256) void phase_kernel(const float* __restrict__ x,
                                                    float* __restrict__ ws) {
    const int tid = blockIdx.x * 256 + threadIdx.x;          // one float4 each
    if (tid >= NPH * BATCH * IN_CH * PADL4) return;
    const int m4   = tid % PADL4;
    int rest       = tid / PADL4;
    const int c    = rest % IN_CH;  rest /= IN_CH;
    const int b    = rest % BATCH;
    const int ph   = rest / BATCH;
    const float* xr = x + ((size_t)b * IN_CH + c) * L_IN;
    const int m = m4 * 4;
    floatx4 v;
#pragma unroll
    for (int i = 0; i < 4; ++i) {
        const int src = m + i + ph;
        ((float*)&v)[i] = (src < L_IN) ? xr[src] : 0.0f;
    }
    *reinterpret_cast<floatx4*>(ws + TAPF + (size_t)tid * 4) = v;
}

// ---- Kernel 3: 2400 blocks x 8 CONSECUTIVE rows (one contiguous 261 KB span
// per block, written sequentially). Swizzle gives each XCD one contiguous
// 78 MB output slice and a 2.1 MB L2-resident xp read slice (4 batches).
// R11 single-variable change vs R8: block->row mapping (was 19200 x 1 row).
__global__ __launch_bounds__(256) void fdc_rows(const float* __restrict__ x,
                                                const float* __restrict__ ws,
                                                float* __restrict__ out) {
    const int bid  = blockIdx.x;
    const int xcd  = bid & 7;
    const int idx  = bid >> 3;                 // 0..299
    const int r0   = xcd * RPX + idx * RPB;    // first of 8 consecutive rows
    const floatx4* xp4 = reinterpret_cast<const floatx4*>(ws + TAPF);

    for (int i = 0; i < RPB; ++i) {
        const int row = r0 + i;
        const int b   = row / NF;
        const int k   = row - b * NF;

        const float* r = ws + (size_t)k * 8;
        const int   c0 = __float_as_int(r[0]), p0 = __float_as_int(r[1]);
        const int   c1 = __float_as_int(r[2]), p1 = __float_as_int(r[3]);
        const float w0 = r[4], w1 = r[5];

        const size_t e0   = (size_t)row * L_OUT;
        float*       orow = out + e0;
        const int    a    = (int)((0u - (unsigned)e0) & 15u);  // head elems to 64B align
        const int    n4   = (L_OUT - a) >> 2;
        const int    tail = L_OUT - a - (n4 << 2);

        // phase/base so that xp4_N[t] == x[b][cN][a + 4t + pN .. +3], 16B-aligned
        const int ph0 = (a + p0) & 3, j0 = (a + p0) >> 2;
        const int ph1 = (a + p1) & 3, j1 = (a + p1) >> 2;
        const floatx4* xp4_0 = xp4 + ((size_t)((ph0 * BATCH + b) * IN_CH + c0)) * PADL4 + j0;
        const floatx4* xp4_1 = xp4 + ((size_t)((ph1 * BATCH + b) * IN_CH + c1)) * PADL4 + j1;

#pragma unroll 2
        for (int t = threadIdx.x; t < n4; t += 256) {
            const floatx4 v0 = xp4_0[t];
            const floatx4 v1 = xp4_1[t];
            const floatx4 v  = w0 * v0 + w1 * v1;
            __builtin_nontemporal_store(v, reinterpret_cast<floatx4*>(orow + a + t * 4));
        }

        // head [0,a) + tail: <= 18 scalars per row, straight from x
        if (threadIdx.x < 24) {
            int elem = -1;
            if ((int)threadIdx.x < a) {
                elem = (int)threadIdx.x;
            } else {
                const int rr = (int)threadIdx.x - a;
                if (rr < tail) elem = a + (n4 << 2) + rr;
            }
            if (elem >= 0) {
                const float* xb = x + (size_t)b * IN_CH * L_IN;
                orow[elem] = w0 * xb[c0 * L_IN + elem + p0] + w1 * xb[c1 * L_IN + elem + p1];
            }
        }
    }
}

extern "C" void kernel_launch(void* const* d_in, const int* in_sizes, int n_in,
                              void* d_out, int out_size, void* d_ws, size_t ws_size,
                              hipStream_t stream) {
    const float* x  = (const float*)d_in[0];   // [32, 4, 8192] fp32
    const float* w  = (const float*)d_in[1];   // [600, 4, 40]  fp32
    float*       o  = (float*)d_out;           // [32, 600, 8153] fp32
    float*       ws = (float*)d_ws;            // taps (19.2 KB) + xp phases (16.8 MB)

    tap_kernel<<<(NF + 255) / 256, 256, 0, stream>>>(w, ws);
    const int nprep = NPH * BATCH * IN_CH * PADL4;            // 1,049,600 float4s
    phase_kernel<<<(nprep + 255) / 256, 256, 0, stream>>>(x, ws);
    fdc_rows<<<NBLK, 256, 0, stream>>>(x, ws, o);             // 2400 blocks x 8 rows
}

// Round 12
// 184.683 us; speedup vs baseline: 1.0097x; 1.0097x over previous
//
#include <hip/hip_runtime.h>

// Problem constants (fixed by the reference).
constexpr int IN_CH = 4;
constexpr int KS    = 40;
constexpr int L_IN  = 8192;
constexpr int L_OUT = L_IN - KS + 1;   // 8153
constexpr int NF    = 600;
constexpr int BATCH = 32;
constexpr int CHUNK = 1024;            // outputs per block along L (4 KB)
constexpr int NCH   = 8;               // chunks per row
constexpr int RSPLIT = 4;              // filter-quarters per (chunk,b)
constexpr int RQ    = NF / RSPLIT;     // 150 filters per block

typedef float floatx4  __attribute__((ext_vector_type(4)));                 // 16B-aligned (stores)
typedef float floatx4u __attribute__((ext_vector_type(4), aligned(4)));     // 4B-aligned (reads)

// ---- Kernel 1: taps. rec[k] = float4{ off0, off1, w0, w1 }, off = c*L_IN + p ----
__global__ void tap_kernel(const float* __restrict__ w, float* __restrict__ ws) {
    const int k = blockIdx.x * 256 + threadIdx.x;
    if (k >= NF) return;
    const float* wk = w + (size_t)k * IN_CH * KS;
    int n = 0; int off[2] = {0, 0}; float val[2] = {0.f, 0.f};
    for (int i = 0; i < IN_CH * KS; ++i) {
        const float v = wk[i];
        if (v != 0.0f && n < 2) { off[n] = (i / KS) * L_IN + (i % KS); val[n] = v; ++n; }
    }
    if (n == 1) { off[1] = off[0]; val[1] = 0.0f; }   // defensive
    float4 r;
    r.x = __int_as_float(off[0]);
    r.y = __int_as_float(off[1]);
    r.z = val[0];
    r.w = val[1];
    *reinterpret_cast<float4*>(ws + (size_t)k * 4) = r;
}

// ---- Kernel 2: block = (l-chunk, filter-quarter, batch). Each block reads
// only 17 KB of x (L1-resident, reused across 150 rows) -> machine-wide HBM
// reads ~4 MB REGARDLESS of XCD dispatch mapping (R12 theory: R8's 46us gap
// over the write floor = xp reads partially missing L2 because the bid%8->XCD
// residency assumption is shaky). Stores: NT, 64B-aligned float4 bursts with
// per-row head/tail peel (proven best path, R6/R8/R9).
__global__ __launch_bounds__(256) void fdc_tile(const float* __restrict__ x,
                                                const float* __restrict__ ws,
                                                float* __restrict__ out) {
    const int base = blockIdx.x * CHUNK;
    const int k0   = blockIdx.y * RQ;
    const int b    = blockIdx.z;
    const float* xb = x + (size_t)b * IN_CH * L_IN;
    const int nvalid = min(CHUNK, L_OUT - base);
    const int t = threadIdx.x;

#pragma unroll 2
    for (int kk = 0; kk < RQ; ++kk) {
        const int k   = k0 + kk;
        const int row = b * NF + k;

        const float4 r  = *reinterpret_cast<const float4*>(ws + (size_t)k * 4);
        const float* x0 = xb + __float_as_int(r.x) + base;
        const float* x1 = xb + __float_as_int(r.y) + base;
        const float  w0 = r.z, w1 = r.w;

        const size_t e0   = (size_t)row * L_OUT + base;
        float*       orow = out + e0;
        const int    a    = (int)((0u - (unsigned)e0) & 15u);  // head elems to 64B align
        const int    n4   = (nvalid - a) >> 2;                 // <= 256 float4s
        const int    tail = nvalid - a - (n4 << 2);            // <= 3

        if (t < n4) {
            const int l = a + t * 4;
            const floatx4u v0 = *reinterpret_cast<const floatx4u*>(x0 + l);
            const floatx4u v1 = *reinterpret_cast<const floatx4u*>(x1 + l);
            floatx4 v;
            v.x = w0 * v0.x + w1 * v1.x;
            v.y = w0 * v0.y + w1 * v1.y;
            v.z = w0 * v0.z + w1 * v1.z;
            v.w = w0 * v0.w + w1 * v1.w;
            __builtin_nontemporal_store(v, reinterpret_cast<floatx4*>(orow + l));
        }
        // head [0,a) + tail [a+4*n4, nvalid): <= 18 scalars, lanes 232..255
        const unsigned idx = (unsigned)t - 232u;
        if (idx < 24u) {
            int elem = -1;
            if ((int)idx < a) {
                elem = (int)idx;
            } else {
                const int rr = (int)idx - a;
                if (rr < tail) elem = a + (n4 << 2) + rr;
            }
            if (elem >= 0) orow[elem] = w0 * x0[elem] + w1 * x1[elem];
        }
    }
}

extern "C" void kernel_launch(void* const* d_in, const int* in_sizes, int n_in,
                              void* d_out, int out_size, void* d_ws, size_t ws_size,
                              hipStream_t stream) {
    const float* x  = (const float*)d_in[0];   // [32, 4, 8192] fp32
    const float* w  = (const float*)d_in[1];   // [600, 4, 40]  fp32
    float*       o  = (float*)d_out;           // [32, 600, 8153] fp32
    float*       ws = (float*)d_ws;            // 600 * float4 tap table (9.6 KB)

    tap_kernel<<<(NF + 255) / 256, 256, 0, stream>>>(w, ws);
    dim3 grid(NCH, RSPLIT, BATCH);             // (8, 4, 32) = 1024 blocks, 4/CU
    fdc_tile<<<grid, 256, 0, stream>>>(x, ws, o);
}

// Round 13
// 148.821 us; speedup vs baseline: 1.2530x; 1.2410x over previous
//
#include <hip/hip_runtime.h>

// Problem constants (fixed by the reference).
constexpr int IN_CH = 4;
constexpr int KS    = 40;
constexpr int L_IN  = 8192;
constexpr int L_OUT = L_IN - KS + 1;   // 8153
constexpr int NF    = 600;
constexpr int BATCH = 32;

typedef float floatx4  __attribute__((ext_vector_type(4)));                 // 16B-aligned (stores)
typedef float floatx4u __attribute__((ext_vector_type(4), aligned(4)));     // 4B-aligned (reads)

// ---- Kernel 1: taps. rec[k] = float4{ off0, off1, w0, w1 }, off = c*L_IN + p ----
__global__ void tap_kernel(const float* __restrict__ w, float* __restrict__ ws) {
    const int k = blockIdx.x * 256 + threadIdx.x;
    if (k >= NF) return;
    const float* wk = w + (size_t)k * IN_CH * KS;
    int n = 0; int off[2] = {0, 0}; float val[2] = {0.f, 0.f};
    for (int i = 0; i < IN_CH * KS; ++i) {
        const float v = wk[i];
        if (v != 0.0f && n < 2) { off[n] = (i / KS) * L_IN + (i % KS); val[n] = v; ++n; }
    }
    if (n == 1) { off[1] = off[0]; val[1] = 0.0f; }   // defensive
    float4 r;
    r.x = __int_as_float(off[0]);
    r.y = __int_as_float(off[1]);
    r.z = val[0];
    r.w = val[1];
    *reinterpret_cast<float4*>(ws + (size_t)k * 4) = r;
}

// ---- Kernel 2: one block per output row (19200 blocks = max store parallelism,
// the proven first-order lever). R13 single-variable change vs R8: reads come
// straight from x via UNALIGNED dwordx4 (no 16.8 MB phase table, no prep
// kernel). x = 4 MB total / 0.5 MB per XCD slice -> unconditionally
// L2-resident regardless of dispatch mapping. NT stores + 64B-aligned bursts
// with head/tail peel (proven best store path).
__global__ __launch_bounds__(256) void fdc_row(const float* __restrict__ x,
                                               const float* __restrict__ ws,
                                               float* __restrict__ out) {
    const int bid = blockIdx.x;
    const int row = (bid & 7) * (NF * BATCH / 8) + (bid >> 3);   // bijective XCD swizzle
    const int b   = row / NF;
    const int k   = row - b * NF;

    const float4 r  = *reinterpret_cast<const float4*>(ws + (size_t)k * 4);
    const float* xb = x + (size_t)b * IN_CH * L_IN;
    const float* x0 = xb + __float_as_int(r.x);
    const float* x1 = xb + __float_as_int(r.y);
    const float  w0 = r.z, w1 = r.w;

    const size_t e0   = (size_t)row * L_OUT;
    float*       orow = out + e0;
    const int    a    = (int)((0u - (unsigned)e0) & 15u);  // head elems to 64B boundary
    const int    n4   = (L_OUT - a) >> 2;                  // aligned float4s (~2036)
    const int    tail = L_OUT - a - (n4 << 2);             // <= 3

#pragma unroll 2
    for (int t = threadIdx.x; t < n4; t += 256) {
        const int l = a + t * 4;
        const floatx4u v0 = *reinterpret_cast<const floatx4u*>(x0 + l);
        const floatx4u v1 = *reinterpret_cast<const floatx4u*>(x1 + l);
        floatx4 v;
        v.x = w0 * v0.x + w1 * v1.x;
        v.y = w0 * v0.y + w1 * v1.y;
        v.z = w0 * v0.z + w1 * v1.z;
        v.w = w0 * v0.w + w1 * v1.w;
        __builtin_nontemporal_store(v, reinterpret_cast<floatx4*>(orow + l));
    }

    // head [0,a) + tail [a+4*n4, L_OUT): <= 18 scalars, once per block
    if (threadIdx.x < 24) {
        int elem = -1;
        if ((int)threadIdx.x < a) {
            elem = (int)threadIdx.x;
        } else {
            const int rr = (int)threadIdx.x - a;
            if (rr < tail) elem = a + (n4 << 2) + rr;
        }
        if (elem >= 0) orow[elem] = w0 * x0[elem] + w1 * x1[elem];
    }
}

extern "C" void kernel_launch(void* const* d_in, const int* in_sizes, int n_in,
                              void* d_out, int out_size, void* d_ws, size_t ws_size,
                              hipStream_t stream) {
    const float* x  = (const float*)d_in[0];   // [32, 4, 8192] fp32
    const float* w  = (const float*)d_in[1];   // [600, 4, 40]  fp32
    float*       o  = (float*)d_out;           // [32, 600, 8153] fp32
    float*       ws = (float*)d_ws;            // 600 * float4 tap table (9.6 KB)

    tap_kernel<<<(NF + 255) / 256, 256, 0, stream>>>(w, ws);
    fdc_row<<<NF * BATCH, 256, 0, stream>>>(x, ws, o);   // 19200 blocks, 1 row each
}